// Round 1
// baseline (322.530 us; speedup 1.0000x reference)
//
#include <hip/hip_runtime.h>
#include <hip/hip_bf16.h>
#include <math.h>

#define B_ 16
#define F_ 512
#define T_ 4000
#define D_ 100    // pooled length
#define E_ 256    // embed dim
#define ROWS (B_*F_)   // 8192

typedef __attribute__((ext_vector_type(8))) short short8;
typedef __attribute__((ext_vector_type(4))) float f32x4;

// ---------------- K1: adaptive avg pool (window=40) + per-row mean ----------
__global__ __launch_bounds__(256) void k_pool(const float* __restrict__ x,
                                              float* __restrict__ pooled,
                                              float* __restrict__ xmean) {
    __shared__ float buf[T_];
    __shared__ float part[4];
    const int row = blockIdx.x;
    const int tid = threadIdx.x;
    const float4* xr = (const float4*)(x + (size_t)row * T_);
    float4* b4 = (float4*)buf;
    for (int i = tid; i < T_/4; i += 256) b4[i] = xr[i];
    __syncthreads();
    float s = 0.f;
    if (tid < 200) {
        const float4* p = (const float4*)(buf + 20 * tid);  // 80B-aligned
        float4 a0 = p[0], a1 = p[1], a2 = p[2], a3 = p[3], a4 = p[4];
        s  = a0.x + a0.y + a0.z + a0.w;
        s += a1.x + a1.y + a1.z + a1.w;
        s += a2.x + a2.y + a2.z + a2.w;
        s += a3.x + a3.y + a3.z + a3.w;
        s += a4.x + a4.y + a4.z + a4.w;
    }
    float other = __shfl_xor(s, 1);
    if (tid < 200 && (tid & 1) == 0)
        pooled[(size_t)row * D_ + (tid >> 1)] = (s + other) * (1.0f/40.0f);
    float tot = s;
    #pragma unroll
    for (int off = 32; off; off >>= 1) tot += __shfl_xor(tot, off);
    if ((tid & 63) == 0) part[tid >> 6] = tot;
    __syncthreads();
    if (tid == 0)
        xmean[row] = (part[0] + part[1] + part[2] + part[3]) * (1.0f/(float)T_);
}

// ---------------- K2: key/query GEMM -> split-bf16 fragments ----------------
// idx = ((b*32 + f/16)*32 + e/8)*128 + (f%16)*8 + (e%8)
__global__ __launch_bounds__(256) void k_kq(const float* __restrict__ pooled,
                                            const float* __restrict__ Wk,
                                            const float* __restrict__ bk,
                                            const float* __restrict__ Wq,
                                            const float* __restrict__ bq,
                                            short* __restrict__ Khi,
                                            short* __restrict__ Klo,
                                            short* __restrict__ Qhi,
                                            short* __restrict__ Qlo) {
    __shared__ float As[D_][65];   // k-major, +1 pad
    __shared__ float Bs[D_][65];
    const int m0 = blockIdx.x * 64;
    const int n0 = blockIdx.y * 64;
    const int tid = threadIdx.x;

    const float* Ab = pooled + (size_t)m0 * D_;
    for (int i = tid; i < 64 * D_; i += 256) {
        int r = i / D_, k = i - r * D_;
        As[k][r] = Ab[i];
    }
    const float* Wb = (n0 < E_) ? (Wk + (size_t)n0 * D_) : (Wq + (size_t)(n0 - E_) * D_);
    for (int i = tid; i < 64 * D_; i += 256) {
        int r = i / D_, k = i - r * D_;
        Bs[k][r] = Wb[i];
    }
    __syncthreads();

    const int tm = (tid >> 4) * 4;
    const int tn = (tid & 15) * 4;
    float acc[4][4] = {};
    for (int k = 0; k < D_; ++k) {
        float a[4], b[4];
        #pragma unroll
        for (int i = 0; i < 4; ++i) a[i] = As[k][tm + i];
        #pragma unroll
        for (int j = 0; j < 4; ++j) b[j] = Bs[k][tn + j];
        #pragma unroll
        for (int i = 0; i < 4; ++i)
            #pragma unroll
            for (int j = 0; j < 4; ++j)
                acc[i][j] = fmaf(a[i], b[j], acc[i][j]);
    }
    const bool is_key = (n0 < E_);   // block-uniform
    short* __restrict__ Phi = is_key ? Khi : Qhi;
    short* __restrict__ Plo = is_key ? Klo : Qlo;
    #pragma unroll
    for (int i = 0; i < 4; ++i)
        #pragma unroll
        for (int jj = 0; jj < 4; ++jj) {
            int n = n0 + tn + jj;
            float bias = is_key ? bk[n] : bq[n - E_];
            float val = acc[i][jj] + bias;
            int mg = m0 + tm + i;
            int b = mg >> 9, f = mg & 511;
            int e = is_key ? n : (n - E_);
            size_t idx = (((size_t)b * 32 + (f >> 4)) * 32 + (e >> 3)) * 128
                       + (size_t)(f & 15) * 8 + (e & 7);
            __hip_bfloat16 h = __float2bfloat16(val);
            float hf = __bfloat162float(h);
            __hip_bfloat16 l = __float2bfloat16(val - hf);
            Phi[idx] = *(short*)&h;
            Plo[idx] = *(short*)&l;
        }
}

// ---------------- K3: fused scores + softmax + fw = att @ xmean -------------
// Grid (F/16, B). 4 waves/block, all covering the SAME 16-row f-tile.
// Wave w streams g-tiles w*8 .. w*8+7, keeping its K fragments in registers.
// S is never materialized: per-row (max, sum, dot-with-xmean) partials are
// combined across waves in LDS. S ~= (hi*hi + hi*lo + lo*hi)/16.
__global__ __launch_bounds__(256) void k_att(const short* __restrict__ Khi,
                                             const short* __restrict__ Klo,
                                             const short* __restrict__ Qhi,
                                             const short* __restrict__ Qlo,
                                             const float* __restrict__ xmean,
                                             float* __restrict__ fw) {
    const int ft  = blockIdx.x;       // f-tile 0..31
    const int b   = blockIdx.y;       // 0..15
    const int tid = threadIdx.x;
    const int w    = tid >> 6;
    const int lane = tid & 63;
    const int col  = lane & 15;       // g within tile
    const int quad = lane >> 4;       // f row group

    __shared__ float xm[512];
    __shared__ float cm[4][16], cs[4][16], cd[4][16];
    xm[tid]       = xmean[((size_t)b << 9) + tid];
    xm[tid + 256] = xmean[((size_t)b << 9) + 256 + tid];

    // K fragments for this f-tile: 8 e-chunks, hi+lo (64 VGPRs)
    const size_t kbase = ((((size_t)b * 32 + ft) << 12)) + (size_t)lane * 8;
    short8 kh[8], kl[8];
    #pragma unroll
    for (int s = 0; s < 8; ++s) {
        kh[s] = *(const short8*)(Khi + kbase + s * 512);
        kl[s] = *(const short8*)(Klo + kbase + s * 512);
    }

    f32x4 acc[8] = {};
    #pragma unroll 2
    for (int j = 0; j < 8; ++j) {
        const size_t qb = ((((size_t)b * 32 + (w * 8 + j)) << 12)) + (size_t)lane * 8;
        #pragma unroll
        for (int s = 0; s < 8; ++s) {
            short8 qh = *(const short8*)(Qhi + qb + s * 512);
            short8 ql = *(const short8*)(Qlo + qb + s * 512);
            acc[j] = __builtin_amdgcn_mfma_f32_16x16x32_bf16(kh[s], qh, acc[j], 0, 0, 0);
            acc[j] = __builtin_amdgcn_mfma_f32_16x16x32_bf16(kh[s], ql, acc[j], 0, 0, 0);
            acc[j] = __builtin_amdgcn_mfma_f32_16x16x32_bf16(kl[s], qh, acc[j], 0, 0, 0);
        }
    }
    __syncthreads();   // xm visible; MFMA results in VGPRs

    // per-row (row = quad*4 + r) softmax partials over this wave's 128 g cols
    #pragma unroll
    for (int r = 0; r < 4; ++r) {
        float v[8];
        #pragma unroll
        for (int j = 0; j < 8; ++j) v[j] = acc[j][r] * (1.0f / 16.0f);  // /SCALE
        float mx = v[0];
        #pragma unroll
        for (int j = 1; j < 8; ++j) mx = fmaxf(mx, v[j]);
        #pragma unroll
        for (int off = 8; off; off >>= 1) mx = fmaxf(mx, __shfl_xor(mx, off));
        float se = 0.f, de = 0.f;
        #pragma unroll
        for (int j = 0; j < 8; ++j) {
            float p = expf(v[j] - mx);
            se += p;
            de += p * xm[(w * 8 + j) * 16 + col];
        }
        #pragma unroll
        for (int off = 8; off; off >>= 1) {
            se += __shfl_xor(se, off);
            de += __shfl_xor(de, off);
        }
        if (col == 0) {
            cm[w][quad * 4 + r] = mx;
            cs[w][quad * 4 + r] = se;
            cd[w][quad * 4 + r] = de;
        }
    }
    __syncthreads();
    if (tid < 16) {
        float M = fmaxf(fmaxf(cm[0][tid], cm[1][tid]), fmaxf(cm[2][tid], cm[3][tid]));
        float S = 0.f, D = 0.f;
        #pragma unroll
        for (int ww = 0; ww < 4; ++ww) {
            float e = expf(cm[ww][tid] - M);
            S += cs[ww][tid] * e;
            D += cd[ww][tid] * e;
        }
        fw[((size_t)b << 9) + ft * 16 + tid] = D / S;
    }
}

// ---------------- K4: per-batch min/max normalize + out = x * fw_n ----------
// Batch min/max recomputed per block from the L2-resident fw array (2 KB),
// removing the k_norm kernel + fwn round-trip.
__global__ __launch_bounds__(256) void k_scale(const float* __restrict__ x,
                                               const float* __restrict__ fw,
                                               float* __restrict__ out) {
    const int row = blockIdx.x;
    const int b   = row >> 9;
    const int tid = threadIdx.x;
    const float* fb = fw + ((size_t)b << 9);
    float v0 = fb[tid], v1 = fb[tid + 256];
    float mi = fminf(v0, v1), ma = fmaxf(v0, v1);
    #pragma unroll
    for (int off = 32; off; off >>= 1) {
        mi = fminf(mi, __shfl_xor(mi, off));
        ma = fmaxf(ma, __shfl_xor(ma, off));
    }
    __shared__ float smi[4], sma[4];
    if ((tid & 63) == 0) { smi[tid >> 6] = mi; sma[tid >> 6] = ma; }
    __syncthreads();
    mi = fminf(fminf(smi[0], smi[1]), fminf(smi[2], smi[3]));
    ma = fmaxf(fmaxf(sma[0], sma[1]), fmaxf(sma[2], sma[3]));
    const float s = (fw[row] - mi) / (ma - mi) + 1e-6f;

    const float4* xr = (const float4*)(x + (size_t)row * T_);
    float4* orow = (float4*)(out + (size_t)row * T_);
    for (int i = tid; i < T_/4; i += 256) {
        float4 v = xr[i];
        v.x *= s; v.y *= s; v.z *= s; v.w *= s;
        orow[i] = v;
    }
}

extern "C" void kernel_launch(void* const* d_in, const int* in_sizes, int n_in,
                              void* d_out, int out_size, void* d_ws, size_t ws_size,
                              hipStream_t stream) {
    const float* x  = (const float*)d_in[0];
    const float* Wk = (const float*)d_in[1];
    const float* bk = (const float*)d_in[2];
    const float* Wq = (const float*)d_in[3];
    const float* bq = (const float*)d_in[4];
    float* out = (float*)d_out;

    float* ws     = (float*)d_ws;
    float* pooled = ws;                                  // 8192*100 f32
    float* xmean  = pooled + (size_t)ROWS * D_;          // 8192 f32
    float* fw     = xmean + ROWS;                        // 8192 f32
    short* Khi    = (short*)(fw + ROWS);                 // 16*32*4096 bf16 bits
    short* Klo    = Khi + (size_t)B_ * 32 * 4096;
    short* Qhi    = Klo + (size_t)B_ * 32 * 4096;
    short* Qlo    = Qhi + (size_t)B_ * 32 * 4096;

    k_pool<<<ROWS, 256, 0, stream>>>(x, pooled, xmean);
    k_kq<<<dim3(ROWS/64, 512/64), 256, 0, stream>>>(pooled, Wk, bk, Wq, bq,
                                                    Khi, Klo, Qhi, Qlo);
    k_att<<<dim3(F_/16, B_), 256, 0, stream>>>(Khi, Klo, Qhi, Qlo, xmean, fw);
    k_scale<<<ROWS, 256, 0, stream>>>(x, fw, out);
}

// Round 2
// 288.199 us; speedup vs baseline: 1.1191x; 1.1191x over previous
//
#include <hip/hip_runtime.h>
#include <hip/hip_bf16.h>
#include <math.h>

#define B_ 16
#define F_ 512
#define T_ 4000
#define D_ 100    // pooled length
#define E2 128    // padded pooled dim for MFMA (100 -> 128)
#define ROWS (B_*F_)   // 8192

typedef __attribute__((ext_vector_type(8))) short short8;
typedef __attribute__((ext_vector_type(4))) float f32x4;

// Fragment layout (verified in previous rounds): for a 16-row tile t of rows
// and K-dim d (0..127):
//   idx = (t*16 + d/8)*128 + (row%16)*8 + (d%8)
// so a wave's lane l at chunk s reads flat [t*2048 + s*512 + l*8 .. +7],
// giving (row = l&15, d = 32s + 8*(l>>4) + i) -- the MFMA 16x16x32 A/B frag.

// ---------------- K1: adaptive avg pool + per-row mean + P fragments --------
__global__ __launch_bounds__(256) void k_pool(const float* __restrict__ x,
                                              short* __restrict__ Phi,
                                              short* __restrict__ Plo,
                                              float* __restrict__ xmean) {
    __shared__ float buf[T_];
    __shared__ float part[4];
    __shared__ float pr[D_];
    const int row = blockIdx.x;
    const int tid = threadIdx.x;
    const float4* xr = (const float4*)(x + (size_t)row * T_);
    float4* b4 = (float4*)buf;
    for (int i = tid; i < T_/4; i += 256) b4[i] = xr[i];
    __syncthreads();
    float s = 0.f;
    if (tid < 200) {
        const float4* p = (const float4*)(buf + 20 * tid);  // 80B-aligned
        float4 a0 = p[0], a1 = p[1], a2 = p[2], a3 = p[3], a4 = p[4];
        s  = a0.x + a0.y + a0.z + a0.w;
        s += a1.x + a1.y + a1.z + a1.w;
        s += a2.x + a2.y + a2.z + a2.w;
        s += a3.x + a3.y + a3.z + a3.w;
        s += a4.x + a4.y + a4.z + a4.w;
    }
    float other = __shfl_xor(s, 1);
    if (tid < 200 && (tid & 1) == 0)
        pr[tid >> 1] = (s + other) * (1.0f/40.0f);
    float tot = s;
    #pragma unroll
    for (int off = 32; off; off >>= 1) tot += __shfl_xor(tot, off);
    if ((tid & 63) == 0) part[tid >> 6] = tot;
    __syncthreads();
    if (tid == 0)
        xmean[row] = (part[0] + part[1] + part[2] + part[3]) * (1.0f/(float)T_);
    // write split-bf16 P fragments (d = tid, pad 100..127 with 0)
    if (tid < E2) {
        const int d = tid;
        float val = (d < D_) ? pr[d] : 0.f;
        __hip_bfloat16 h = __float2bfloat16(val);
        float hf = __bfloat162float(h);
        __hip_bfloat16 l = __float2bfloat16(val - hf);
        const int bb = row >> 9, f = row & 511;
        size_t idx = (((size_t)bb * 32 + (f >> 4)) * 16 + (d >> 3)) * 128
                   + (size_t)(f & 15) * 8 + (d & 7);
        Phi[idx] = *(short*)&h;
        Plo[idx] = *(short*)&l;
    }
}

// ---------------- K2: M = Wk^T Wq (100x100, padded to 128x128 frags),
//                      v = Wq^T bk ------------------------------------------
__global__ __launch_bounds__(256) void k_prep(const float* __restrict__ Wk,
                                              const float* __restrict__ Wq,
                                              const float* __restrict__ bk,
                                              short* __restrict__ Mhi,
                                              short* __restrict__ Mlo,
                                              float* __restrict__ v) {
    const int t = blockIdx.x * 256 + threadIdx.x;
    if (t < E2 * E2) {
        const int dp   = t >> 7;    // d' (K-dim) 0..127
        const int dout = t & 127;   // output dim 0..127
        float acc = 0.f;
        if (dp < D_ && dout < D_) {
            #pragma unroll 8
            for (int e = 0; e < 256; ++e)
                acc = fmaf(Wk[e * D_ + dp], Wq[e * D_ + dout], acc);
        }
        __hip_bfloat16 h = __float2bfloat16(acc);
        float hf = __bfloat162float(h);
        __hip_bfloat16 l = __float2bfloat16(acc - hf);
        // B-frag layout: tile = dout/16, row-in-tile = dout%16, K = dp
        size_t idx = ((size_t)(dout >> 4) * 16 + (dp >> 3)) * 128
                   + (size_t)(dout & 15) * 8 + (dp & 7);
        Mhi[idx] = *(short*)&h;
        Mlo[idx] = *(short*)&l;
    } else if (t < E2 * E2 + E2) {
        const int d = t - E2 * E2;
        float acc = 0.f;
        if (d < D_) {
            #pragma unroll 8
            for (int e = 0; e < 256; ++e)
                acc = fmaf(Wq[e * D_ + d], bk[e], acc);
        }
        v[d] = acc;
    }
}

// ---------------- K3: fused Y = P@M + v, S = Y@P^T, softmax, fw -------------
// Grid (32 f-tiles, 16 batches), 512 threads = 8 waves.
// Softmax over g of S[f,g] equals reference up to a per-row constant
// (a_f + bk.bq), which cancels. c_g is folded in via Y += v.
__global__ __launch_bounds__(512) void k_att(const short* __restrict__ Phi,
                                             const short* __restrict__ Plo,
                                             const short* __restrict__ Mhi,
                                             const short* __restrict__ Mlo,
                                             const float* __restrict__ v,
                                             const float* __restrict__ xmean,
                                             float* __restrict__ fw) {
    const int ft  = blockIdx.x;       // f-tile 0..31
    const int b   = blockIdx.y;       // 0..15
    const int tid  = threadIdx.x;
    const int w    = tid >> 6;        // wave 0..7
    const int lane = tid & 63;
    const int col  = lane & 15;
    const int quad = lane >> 4;

    __shared__ float Yt[16][136];     // Y-tile fp32, padded stride
    __shared__ float xm[512];
    __shared__ float cm[8][16], cs[8][16], cd[8][16];
    xm[tid] = xmean[((size_t)b << 9) + tid];

    // ---- A-operand: this f-tile's P fragments (used for Y-MFMA) ----
    const size_t pbase = (((size_t)b * 32 + ft) << 11) + (size_t)lane * 8;
    short8 ph[4], pl[4];
    #pragma unroll
    for (int s = 0; s < 4; ++s) {
        ph[s] = *(const short8*)(Phi + pbase + s * 512);
        pl[s] = *(const short8*)(Plo + pbase + s * 512);
    }

    // ---- Y-tile: wave w computes dout-tile dt = w (16 cols) ----
    {
        f32x4 yacc = {};
        const size_t mbase = (size_t)w * 2048 + (size_t)lane * 8;
        #pragma unroll
        for (int s = 0; s < 4; ++s) {
            short8 mh = *(const short8*)(Mhi + mbase + s * 512);
            short8 ml = *(const short8*)(Mlo + mbase + s * 512);
            yacc = __builtin_amdgcn_mfma_f32_16x16x32_bf16(ph[s], mh, yacc, 0, 0, 0);
            yacc = __builtin_amdgcn_mfma_f32_16x16x32_bf16(ph[s], ml, yacc, 0, 0, 0);
            yacc = __builtin_amdgcn_mfma_f32_16x16x32_bf16(pl[s], mh, yacc, 0, 0, 0);
        }
        const int dout = w * 16 + col;
        const float vl = v[dout];
        #pragma unroll
        for (int r = 0; r < 4; ++r) {
            float val = yacc[r] + vl;
            if (dout == D_) val = 1.0f;   // harmless ext slot (P pad is 0 there)
            Yt[quad * 4 + r][dout] = val;
        }
    }
    __syncthreads();

    // ---- read Y-tile back as split-bf16 A-fragments ----
    short8 yh[4], yl[4];
    #pragma unroll
    for (int s = 0; s < 4; ++s) {
        const float* src = &Yt[lane & 15][s * 32 + quad * 8];
        f32x4 u0 = *(const f32x4*)src;
        f32x4 u1 = *(const f32x4*)(src + 4);
        float vs[8] = {u0.x, u0.y, u0.z, u0.w, u1.x, u1.y, u1.z, u1.w};
        short8 hh, ll;
        #pragma unroll
        for (int i = 0; i < 8; ++i) {
            float xv = vs[i];
            __hip_bfloat16 h = __float2bfloat16(xv);
            float hf = __bfloat162float(h);
            __hip_bfloat16 lo = __float2bfloat16(xv - hf);
            hh[i] = *(short*)&h;
            ll[i] = *(short*)&lo;
        }
        yh[s] = hh; yl[s] = ll;
    }

    // ---- S-tiles: wave w covers g-tiles w*4 .. w*4+3 ----
    f32x4 acc[4] = {};
    #pragma unroll
    for (int j = 0; j < 4; ++j) {
        const int gt = w * 4 + j;
        const size_t qb = (((size_t)b * 32 + gt) << 11) + (size_t)lane * 8;
        #pragma unroll
        for (int s = 0; s < 4; ++s) {
            short8 qh = *(const short8*)(Phi + qb + s * 512);
            short8 ql = *(const short8*)(Plo + qb + s * 512);
            acc[j] = __builtin_amdgcn_mfma_f32_16x16x32_bf16(yh[s], qh, acc[j], 0, 0, 0);
            acc[j] = __builtin_amdgcn_mfma_f32_16x16x32_bf16(yh[s], ql, acc[j], 0, 0, 0);
            acc[j] = __builtin_amdgcn_mfma_f32_16x16x32_bf16(yl[s], qh, acc[j], 0, 0, 0);
        }
    }

    // ---- streaming softmax partials over this wave's 64 g-cols ----
    #pragma unroll
    for (int r = 0; r < 4; ++r) {
        float vv[4];
        #pragma unroll
        for (int j = 0; j < 4; ++j) vv[j] = acc[j][r] * (1.0f / 16.0f);  // /SCALE
        float mx = fmaxf(fmaxf(vv[0], vv[1]), fmaxf(vv[2], vv[3]));
        #pragma unroll
        for (int off = 8; off; off >>= 1) mx = fmaxf(mx, __shfl_xor(mx, off));
        float se = 0.f, de = 0.f;
        #pragma unroll
        for (int j = 0; j < 4; ++j) {
            float p = expf(vv[j] - mx);
            se += p;
            de += p * xm[(w * 4 + j) * 16 + col];
        }
        #pragma unroll
        for (int off = 8; off; off >>= 1) {
            se += __shfl_xor(se, off);
            de += __shfl_xor(de, off);
        }
        if (col == 0) {
            cm[w][quad * 4 + r] = mx;
            cs[w][quad * 4 + r] = se;
            cd[w][quad * 4 + r] = de;
        }
    }
    __syncthreads();
    if (tid < 16) {
        float Mx = cm[0][tid];
        #pragma unroll
        for (int ww = 1; ww < 8; ++ww) Mx = fmaxf(Mx, cm[ww][tid]);
        float Sx = 0.f, Dx = 0.f;
        #pragma unroll
        for (int ww = 0; ww < 8; ++ww) {
            float e = expf(cm[ww][tid] - Mx);
            Sx += cs[ww][tid] * e;
            Dx += cd[ww][tid] * e;
        }
        fw[((size_t)b << 9) + ft * 16 + tid] = Dx / Sx;
    }
}

// ---------------- K4: per-batch min/max normalize + out = x * fw_n ----------
__global__ __launch_bounds__(256) void k_scale(const float* __restrict__ x,
                                               const float* __restrict__ fw,
                                               float* __restrict__ out) {
    const int row = blockIdx.x;
    const int b   = row >> 9;
    const int tid = threadIdx.x;
    const float* fb = fw + ((size_t)b << 9);
    float v0 = fb[tid], v1 = fb[tid + 256];
    float mi = fminf(v0, v1), ma = fmaxf(v0, v1);
    #pragma unroll
    for (int off = 32; off; off >>= 1) {
        mi = fminf(mi, __shfl_xor(mi, off));
        ma = fmaxf(ma, __shfl_xor(ma, off));
    }
    __shared__ float smi[4], sma[4];
    if ((tid & 63) == 0) { smi[tid >> 6] = mi; sma[tid >> 6] = ma; }
    __syncthreads();
    mi = fminf(fminf(smi[0], smi[1]), fminf(smi[2], smi[3]));
    ma = fmaxf(fmaxf(sma[0], sma[1]), fmaxf(sma[2], sma[3]));
    const float s = (fw[row] - mi) / (ma - mi) + 1e-6f;

    const float4* xr = (const float4*)(x + (size_t)row * T_);
    float4* orow = (float4*)(out + (size_t)row * T_);
    for (int i = tid; i < T_/4; i += 256) {
        float4 vv = xr[i];
        vv.x *= s; vv.y *= s; vv.z *= s; vv.w *= s;
        orow[i] = vv;
    }
}

extern "C" void kernel_launch(void* const* d_in, const int* in_sizes, int n_in,
                              void* d_out, int out_size, void* d_ws, size_t ws_size,
                              hipStream_t stream) {
    const float* x  = (const float*)d_in[0];
    const float* Wk = (const float*)d_in[1];
    const float* bk = (const float*)d_in[2];
    const float* Wq = (const float*)d_in[3];
    const float* bq = (const float*)d_in[4];
    (void)bq;  // cancels in softmax (row-constant); not needed
    float* out = (float*)d_out;

    float* ws    = (float*)d_ws;
    float* xmean = ws;                                   // 8192 f32
    float* fw    = xmean + ROWS;                         // 8192 f32
    float* v     = fw + ROWS;                            // 128 f32
    short* Mhi   = (short*)(v + E2);                     // 128*128 bf16 bits
    short* Mlo   = Mhi + (size_t)E2 * E2;
    short* Phi   = Mlo + (size_t)E2 * E2;                // 8192*128 bf16 bits
    short* Plo   = Phi + (size_t)ROWS * E2;

    k_pool<<<ROWS, 256, 0, stream>>>(x, Phi, Plo, xmean);
    k_prep<<<(E2 * E2 + E2 + 255) / 256, 256, 0, stream>>>(Wk, Wq, bk, Mhi, Mlo, v);
    k_att<<<dim3(F_/16, B_), 512, 0, stream>>>(Phi, Plo, Mhi, Mlo, v, xmean, fw);
    k_scale<<<ROWS, 256, 0, stream>>>(x, fw, out);
}

// Round 3
// 281.972 us; speedup vs baseline: 1.1438x; 1.0221x over previous
//
#include <hip/hip_runtime.h>
#include <hip/hip_bf16.h>
#include <math.h>

#define B_ 16
#define F_ 512
#define T_ 4000
#define D_ 100    // pooled length
#define E2 128    // padded pooled dim for MFMA (100 -> 128)
#define ROWS (B_*F_)   // 8192
#define PREP_BLOCKS ((E2*E2 + E2 + 255) / 256)   // 65

typedef __attribute__((ext_vector_type(8))) short short8;
typedef __attribute__((ext_vector_type(4))) float f32x4;

// Fragment layout (verified): for a 16-row tile t and K-dim d (0..127):
//   idx = (t*16 + d/8)*128 + (row%16)*8 + (d%8)
// A wave's lane l at chunk s reads flat [t*2048 + s*512 + l*8 .. +7]
// = MFMA 16x16x32 A/B fragment (row = l&15, d = 32s + 8*(l>>4) + i).

// ---------------- K1: pool + per-row mean + P frags; tail blocks do prep ----
__global__ __launch_bounds__(256) void k_pool(const float* __restrict__ x,
                                              const float* __restrict__ Wk,
                                              const float* __restrict__ Wq,
                                              const float* __restrict__ bk,
                                              short* __restrict__ Phi,
                                              short* __restrict__ Plo,
                                              short* __restrict__ Mhi,
                                              short* __restrict__ Mlo,
                                              float* __restrict__ v,
                                              float* __restrict__ xmean) {
    __shared__ float buf[T_];
    __shared__ float part[4];
    __shared__ float pr[D_];
    const int tid = threadIdx.x;

    if (blockIdx.x >= ROWS) {
        // ---- prep path: M = Wk^T Wq (padded 128x128 frags), v = Wq^T bk ----
        const int t = (blockIdx.x - ROWS) * 256 + tid;
        if (t < E2 * E2) {
            const int dp   = t >> 7;    // K-dim 0..127
            const int dout = t & 127;   // output dim 0..127
            float acc = 0.f;
            if (dp < D_ && dout < D_) {
                #pragma unroll 8
                for (int e = 0; e < 256; ++e)
                    acc = fmaf(Wk[e * D_ + dp], Wq[e * D_ + dout], acc);
            }
            __hip_bfloat16 h = __float2bfloat16(acc);
            float hf = __bfloat162float(h);
            __hip_bfloat16 l = __float2bfloat16(acc - hf);
            size_t idx = ((size_t)(dout >> 4) * 16 + (dp >> 3)) * 128
                       + (size_t)(dout & 15) * 8 + (dp & 7);
            Mhi[idx] = *(short*)&h;
            Mlo[idx] = *(short*)&l;
        } else if (t < E2 * E2 + E2) {
            const int d = t - E2 * E2;
            float acc = 0.f;
            if (d < D_) {
                #pragma unroll 8
                for (int e = 0; e < 256; ++e)
                    acc = fmaf(Wq[e * D_ + d], bk[e], acc);
            }
            v[d] = acc;
        }
        return;
    }

    // ---- pool path ----
    const int row = blockIdx.x;
    const float4* xr = (const float4*)(x + (size_t)row * T_);
    float4* b4 = (float4*)buf;
    for (int i = tid; i < T_/4; i += 256) b4[i] = xr[i];
    __syncthreads();
    float s = 0.f;
    if (tid < 200) {
        const float4* p = (const float4*)(buf + 20 * tid);  // 80B-aligned
        float4 a0 = p[0], a1 = p[1], a2 = p[2], a3 = p[3], a4 = p[4];
        s  = a0.x + a0.y + a0.z + a0.w;
        s += a1.x + a1.y + a1.z + a1.w;
        s += a2.x + a2.y + a2.z + a2.w;
        s += a3.x + a3.y + a3.z + a3.w;
        s += a4.x + a4.y + a4.z + a4.w;
    }
    float other = __shfl_xor(s, 1);
    if (tid < 200 && (tid & 1) == 0)
        pr[tid >> 1] = (s + other) * (1.0f/40.0f);
    float tot = s;
    #pragma unroll
    for (int off = 32; off; off >>= 1) tot += __shfl_xor(tot, off);
    if ((tid & 63) == 0) part[tid >> 6] = tot;
    __syncthreads();
    if (tid == 0)
        xmean[row] = (part[0] + part[1] + part[2] + part[3]) * (1.0f/(float)T_);
    // split-bf16 P fragments (d = tid, pad 100..127 with 0)
    if (tid < E2) {
        const int d = tid;
        float val = (d < D_) ? pr[d] : 0.f;
        __hip_bfloat16 h = __float2bfloat16(val);
        float hf = __bfloat162float(h);
        __hip_bfloat16 l = __float2bfloat16(val - hf);
        const int bb = row >> 9, f = row & 511;
        size_t idx = (((size_t)bb * 32 + (f >> 4)) * 16 + (d >> 3)) * 128
                   + (size_t)(f & 15) * 8 + (d & 7);
        Phi[idx] = *(short*)&h;
        Plo[idx] = *(short*)&l;
    }
}

// ---------------- K2: fused Y = P@M + v, S = Y@P^T, softmax, fw -------------
// Grid (32 f-tiles, 16 batches), 512 threads = 8 waves.
// softmax over g of S[f,g] equals reference up to a per-row constant
// (a_f + bk.bq), which cancels. c_g folded in via Y += v.
__global__ __launch_bounds__(512) void k_att(const short* __restrict__ Phi,
                                             const short* __restrict__ Plo,
                                             const short* __restrict__ Mhi,
                                             const short* __restrict__ Mlo,
                                             const float* __restrict__ v,
                                             const float* __restrict__ xmean,
                                             float* __restrict__ fw) {
    const int ft  = blockIdx.x;       // f-tile 0..31
    const int b   = blockIdx.y;       // 0..15
    const int tid  = threadIdx.x;
    const int w    = tid >> 6;        // wave 0..7
    const int lane = tid & 63;
    const int col  = lane & 15;
    const int quad = lane >> 4;

    __shared__ float Yt[16][136];     // Y-tile fp32, padded stride
    __shared__ float xm[512];
    __shared__ float cm[8][16], cs[8][16], cd[8][16];
    xm[tid] = xmean[((size_t)b << 9) + tid];

    // ---- A-operand: this f-tile's P fragments ----
    const size_t pbase = (((size_t)b * 32 + ft) << 11) + (size_t)lane * 8;
    short8 ph[4], pl[4];
    #pragma unroll
    for (int s = 0; s < 4; ++s) {
        ph[s] = *(const short8*)(Phi + pbase + s * 512);
        pl[s] = *(const short8*)(Plo + pbase + s * 512);
    }

    // ---- Y-tile: wave w computes dout-tile w (16 cols) ----
    {
        f32x4 yacc = {};
        const size_t mbase = (size_t)w * 2048 + (size_t)lane * 8;
        #pragma unroll
        for (int s = 0; s < 4; ++s) {
            short8 mh = *(const short8*)(Mhi + mbase + s * 512);
            short8 ml = *(const short8*)(Mlo + mbase + s * 512);
            yacc = __builtin_amdgcn_mfma_f32_16x16x32_bf16(ph[s], mh, yacc, 0, 0, 0);
            yacc = __builtin_amdgcn_mfma_f32_16x16x32_bf16(ph[s], ml, yacc, 0, 0, 0);
            yacc = __builtin_amdgcn_mfma_f32_16x16x32_bf16(pl[s], mh, yacc, 0, 0, 0);
        }
        const int dout = w * 16 + col;
        const float vl = v[dout];
        #pragma unroll
        for (int r = 0; r < 4; ++r) {
            float val = yacc[r] + vl;
            if (dout == D_) val = 1.0f;   // harmless ext slot (P pad is 0 there)
            Yt[quad * 4 + r][dout] = val;
        }
    }
    __syncthreads();

    // ---- read Y-tile back as split-bf16 A-fragments ----
    short8 yh[4], yl[4];
    #pragma unroll
    for (int s = 0; s < 4; ++s) {
        const float* src = &Yt[lane & 15][s * 32 + quad * 8];
        f32x4 u0 = *(const f32x4*)src;
        f32x4 u1 = *(const f32x4*)(src + 4);
        float vs[8] = {u0.x, u0.y, u0.z, u0.w, u1.x, u1.y, u1.z, u1.w};
        short8 hh, ll;
        #pragma unroll
        for (int i = 0; i < 8; ++i) {
            float xv = vs[i];
            __hip_bfloat16 h = __float2bfloat16(xv);
            float hf = __bfloat162float(h);
            __hip_bfloat16 lo = __float2bfloat16(xv - hf);
            hh[i] = *(short*)&h;
            ll[i] = *(short*)&lo;
        }
        yh[s] = hh; yl[s] = ll;
    }

    // ---- S-tiles: wave w covers g-tiles w*4 .. w*4+3 ----
    f32x4 acc[4] = {};
    #pragma unroll
    for (int j = 0; j < 4; ++j) {
        const int gt = w * 4 + j;
        const size_t qb = (((size_t)b * 32 + gt) << 11) + (size_t)lane * 8;
        #pragma unroll
        for (int s = 0; s < 4; ++s) {
            short8 qh = *(const short8*)(Phi + qb + s * 512);
            short8 ql = *(const short8*)(Plo + qb + s * 512);
            acc[j] = __builtin_amdgcn_mfma_f32_16x16x32_bf16(yh[s], qh, acc[j], 0, 0, 0);
            acc[j] = __builtin_amdgcn_mfma_f32_16x16x32_bf16(yh[s], ql, acc[j], 0, 0, 0);
            acc[j] = __builtin_amdgcn_mfma_f32_16x16x32_bf16(yl[s], qh, acc[j], 0, 0, 0);
        }
    }

    // ---- streaming softmax partials over this wave's 64 g-cols ----
    #pragma unroll
    for (int r = 0; r < 4; ++r) {
        float vv[4];
        #pragma unroll
        for (int j = 0; j < 4; ++j) vv[j] = acc[j][r] * (1.0f / 16.0f);  // /SCALE
        float mx = fmaxf(fmaxf(vv[0], vv[1]), fmaxf(vv[2], vv[3]));
        #pragma unroll
        for (int off = 8; off; off >>= 1) mx = fmaxf(mx, __shfl_xor(mx, off));
        float se = 0.f, de = 0.f;
        #pragma unroll
        for (int j = 0; j < 4; ++j) {
            float p = expf(vv[j] - mx);
            se += p;
            de += p * xm[(w * 4 + j) * 16 + col];
        }
        #pragma unroll
        for (int off = 8; off; off >>= 1) {
            se += __shfl_xor(se, off);
            de += __shfl_xor(de, off);
        }
        if (col == 0) {
            cm[w][quad * 4 + r] = mx;
            cs[w][quad * 4 + r] = se;
            cd[w][quad * 4 + r] = de;
        }
    }
    __syncthreads();
    if (tid < 16) {
        float Mx = cm[0][tid];
        #pragma unroll
        for (int ww = 1; ww < 8; ++ww) Mx = fmaxf(Mx, cm[ww][tid]);
        float Sx = 0.f, Dx = 0.f;
        #pragma unroll
        for (int ww = 0; ww < 8; ++ww) {
            float e = expf(cm[ww][tid] - Mx);
            Sx += cs[ww][tid] * e;
            Dx += cd[ww][tid] * e;
        }
        fw[((size_t)b << 9) + ft * 16 + tid] = Dx / Sx;
    }
}

// ---------------- K3: per-batch min/max normalize + out = x * fw_n ----------
__global__ __launch_bounds__(256) void k_scale(const float* __restrict__ x,
                                               const float* __restrict__ fw,
                                               float* __restrict__ out) {
    const int row = blockIdx.x;
    const int b   = row >> 9;
    const int tid = threadIdx.x;
    const float* fb = fw + ((size_t)b << 9);
    float v0 = fb[tid], v1 = fb[tid + 256];
    float mi = fminf(v0, v1), ma = fmaxf(v0, v1);
    #pragma unroll
    for (int off = 32; off; off >>= 1) {
        mi = fminf(mi, __shfl_xor(mi, off));
        ma = fmaxf(ma, __shfl_xor(ma, off));
    }
    __shared__ float smi[4], sma[4];
    if ((tid & 63) == 0) { smi[tid >> 6] = mi; sma[tid >> 6] = ma; }
    __syncthreads();
    mi = fminf(fminf(smi[0], smi[1]), fminf(smi[2], smi[3]));
    ma = fmaxf(fmaxf(sma[0], sma[1]), fmaxf(sma[2], sma[3]));
    const float s = (fw[row] - mi) / (ma - mi) + 1e-6f;

    const float4* xr = (const float4*)(x + (size_t)row * T_);
    float4* orow = (float4*)(out + (size_t)row * T_);
    for (int i = tid; i < T_/4; i += 256) {
        float4 vv = xr[i];
        vv.x *= s; vv.y *= s; vv.z *= s; vv.w *= s;
        orow[i] = vv;
    }
}

extern "C" void kernel_launch(void* const* d_in, const int* in_sizes, int n_in,
                              void* d_out, int out_size, void* d_ws, size_t ws_size,
                              hipStream_t stream) {
    const float* x  = (const float*)d_in[0];
    const float* Wk = (const float*)d_in[1];
    const float* bk = (const float*)d_in[2];
    const float* Wq = (const float*)d_in[3];
    const float* bq = (const float*)d_in[4];
    (void)bq;  // cancels in softmax (row-constant); not needed
    float* out = (float*)d_out;

    float* ws    = (float*)d_ws;
    float* xmean = ws;                                   // 8192 f32
    float* fw    = xmean + ROWS;                         // 8192 f32
    float* v     = fw + ROWS;                            // 128 f32
    short* Mhi   = (short*)(v + E2);                     // 128*128 bf16 bits
    short* Mlo   = Mhi + (size_t)E2 * E2;
    short* Phi   = Mlo + (size_t)E2 * E2;                // 8192*128 bf16 bits
    short* Plo   = Phi + (size_t)ROWS * E2;

    k_pool<<<ROWS + PREP_BLOCKS, 256, 0, stream>>>(x, Wk, Wq, bk,
                                                   Phi, Plo, Mhi, Mlo, v, xmean);
    k_att<<<dim3(F_/16, B_), 512, 0, stream>>>(Phi, Plo, Mhi, Mlo, v, xmean, fw);
    k_scale<<<ROWS, 256, 0, stream>>>(x, fw, out);
}

// Round 5
// 278.949 us; speedup vs baseline: 1.1562x; 1.0108x over previous
//
#include <hip/hip_runtime.h>
#include <hip/hip_bf16.h>
#include <math.h>

#define B_ 16
#define F_ 512
#define T_ 4000
#define D_ 100    // pooled length
#define E2 128    // padded pooled dim for MFMA (100 -> 128)
#define ROWS (B_*F_)   // 8192
#define PREP_BLOCKS ((E2*E2 + E2 + 255) / 256)   // 65

typedef __attribute__((ext_vector_type(8))) short short8;
typedef __attribute__((ext_vector_type(4))) float f32x4;

// Fragment layout (verified): for a 16-row tile t and K-dim d (0..127):
//   idx = (t*16 + d/8)*128 + (row%16)*8 + (d%8)
// A wave's lane l at chunk s reads flat [t*2048 + s*512 + l*8 .. +7]
// = MFMA 16x16x32 A/B fragment (row = l&15, d = 32s + 8*(l>>4) + i).

// ---------------- K1: pool + per-row mean + P frags; tail blocks do prep ----
__global__ __launch_bounds__(256) void k_pool(const float* __restrict__ x,
                                              const float* __restrict__ Wk,
                                              const float* __restrict__ Wq,
                                              const float* __restrict__ bk,
                                              short* __restrict__ Phi,
                                              short* __restrict__ Plo,
                                              short* __restrict__ Mhi,
                                              short* __restrict__ Mlo,
                                              float* __restrict__ v,
                                              float* __restrict__ xmean) {
    __shared__ float buf[T_];
    __shared__ float part[4];
    __shared__ float pr[D_];
    const int tid = threadIdx.x;

    if (blockIdx.x >= ROWS) {
        // ---- prep path: M = Wk^T Wq (padded 128x128 frags), v = Wq^T bk ----
        const int t = (blockIdx.x - ROWS) * 256 + tid;
        if (t < E2 * E2) {
            const int dp   = t >> 7;    // K-dim 0..127
            const int dout = t & 127;   // output dim 0..127
            float acc = 0.f;
            if (dp < D_ && dout < D_) {
                #pragma unroll 8
                for (int e = 0; e < 256; ++e)
                    acc = fmaf(Wk[e * D_ + dp], Wq[e * D_ + dout], acc);
            }
            __hip_bfloat16 h = __float2bfloat16(acc);
            float hf = __bfloat162float(h);
            __hip_bfloat16 l = __float2bfloat16(acc - hf);
            size_t idx = ((size_t)(dout >> 4) * 16 + (dp >> 3)) * 128
                       + (size_t)(dout & 15) * 8 + (dp & 7);
            Mhi[idx] = *(short*)&h;
            Mlo[idx] = *(short*)&l;
        } else if (t < E2 * E2 + E2) {
            const int d = t - E2 * E2;
            float acc = 0.f;
            if (d < D_) {
                #pragma unroll 8
                for (int e = 0; e < 256; ++e)
                    acc = fmaf(Wq[e * D_ + d], bk[e], acc);
            }
            v[d] = acc;
        }
        return;
    }

    // ---- pool path ----
    const int row = blockIdx.x;
    const float4* xr = (const float4*)(x + (size_t)row * T_);
    float4* b4 = (float4*)buf;
    for (int i = tid; i < T_/4; i += 256) b4[i] = xr[i];
    __syncthreads();
    float s = 0.f;
    if (tid < 200) {
        const float4* p = (const float4*)(buf + 20 * tid);  // 80B-aligned
        float4 a0 = p[0], a1 = p[1], a2 = p[2], a3 = p[3], a4 = p[4];
        s  = a0.x + a0.y + a0.z + a0.w;
        s += a1.x + a1.y + a1.z + a1.w;
        s += a2.x + a2.y + a2.z + a2.w;
        s += a3.x + a3.y + a3.z + a3.w;
        s += a4.x + a4.y + a4.z + a4.w;
    }
    float other = __shfl_xor(s, 1);
    if (tid < 200 && (tid & 1) == 0)
        pr[tid >> 1] = (s + other) * (1.0f/40.0f);
    float tot = s;
    #pragma unroll
    for (int off = 32; off; off >>= 1) tot += __shfl_xor(tot, off);
    if ((tid & 63) == 0) part[tid >> 6] = tot;
    __syncthreads();
    if (tid == 0)
        xmean[row] = (part[0] + part[1] + part[2] + part[3]) * (1.0f/(float)T_);
    // split-bf16 P fragments (d = tid, pad 100..127 with 0)
    if (tid < E2) {
        const int d = tid;
        float val = (d < D_) ? pr[d] : 0.f;
        __hip_bfloat16 h = __float2bfloat16(val);
        float hf = __bfloat162float(h);
        __hip_bfloat16 l = __float2bfloat16(val - hf);
        const int bb = row >> 9, f = row & 511;
        size_t idx = (((size_t)bb * 32 + (f >> 4)) * 16 + (d >> 3)) * 128
                   + (size_t)(f & 15) * 8 + (d & 7);
        Phi[idx] = *(short*)&h;
        Plo[idx] = *(short*)&l;
    }
}

// ---------------- K2: fused Y = P@M + v, S = Y@P^T, softmax, fw -------------
// Grid (32 f-tiles, 16 batches), 512 threads = 8 waves.
// softmax over g of S[f,g] equals reference up to a per-row constant
// (a_f + bk.bq), which cancels. c_g folded in via Y += v.
__global__ __launch_bounds__(512) void k_att(const short* __restrict__ Phi,
                                             const short* __restrict__ Plo,
                                             const short* __restrict__ Mhi,
                                             const short* __restrict__ Mlo,
                                             const float* __restrict__ v,
                                             const float* __restrict__ xmean,
                                             float* __restrict__ fw) {
    const int ft  = blockIdx.x;       // f-tile 0..31
    const int b   = blockIdx.y;       // 0..15
    const int tid  = threadIdx.x;
    const int w    = tid >> 6;        // wave 0..7
    const int lane = tid & 63;
    const int col  = lane & 15;
    const int quad = lane >> 4;

    __shared__ float Yt[16][136];     // Y-tile fp32, padded stride
    __shared__ float xm[512];
    __shared__ float cm[8][16], cs[8][16], cd[8][16];
    xm[tid] = xmean[((size_t)b << 9) + tid];

    // ---- A-operand: this f-tile's P fragments ----
    const size_t pbase = (((size_t)b * 32 + ft) << 11) + (size_t)lane * 8;
    short8 ph[4], pl[4];
    #pragma unroll
    for (int s = 0; s < 4; ++s) {
        ph[s] = *(const short8*)(Phi + pbase + s * 512);
        pl[s] = *(const short8*)(Plo + pbase + s * 512);
    }

    // ---- Y-tile: wave w computes dout-tile w (16 cols) ----
    {
        f32x4 yacc = {};
        const size_t mbase = (size_t)w * 2048 + (size_t)lane * 8;
        #pragma unroll
        for (int s = 0; s < 4; ++s) {
            short8 mh = *(const short8*)(Mhi + mbase + s * 512);
            short8 ml = *(const short8*)(Mlo + mbase + s * 512);
            yacc = __builtin_amdgcn_mfma_f32_16x16x32_bf16(ph[s], mh, yacc, 0, 0, 0);
            yacc = __builtin_amdgcn_mfma_f32_16x16x32_bf16(ph[s], ml, yacc, 0, 0, 0);
            yacc = __builtin_amdgcn_mfma_f32_16x16x32_bf16(pl[s], mh, yacc, 0, 0, 0);
        }
        const int dout = w * 16 + col;
        const float vl = v[dout];
        #pragma unroll
        for (int r = 0; r < 4; ++r) {
            float val = yacc[r] + vl;
            if (dout == D_) val = 1.0f;   // harmless ext slot (P pad is 0 there)
            Yt[quad * 4 + r][dout] = val;
        }
    }
    __syncthreads();

    // ---- read Y-tile back as split-bf16 A-fragments ----
    short8 yh[4], yl[4];
    #pragma unroll
    for (int s = 0; s < 4; ++s) {
        const float* src = &Yt[lane & 15][s * 32 + quad * 8];
        f32x4 u0 = *(const f32x4*)src;
        f32x4 u1 = *(const f32x4*)(src + 4);
        float vs[8] = {u0.x, u0.y, u0.z, u0.w, u1.x, u1.y, u1.z, u1.w};
        short8 hh, ll;
        #pragma unroll
        for (int i = 0; i < 8; ++i) {
            float xv = vs[i];
            __hip_bfloat16 h = __float2bfloat16(xv);
            float hf = __bfloat162float(h);
            __hip_bfloat16 lo = __float2bfloat16(xv - hf);
            hh[i] = *(short*)&h;
            ll[i] = *(short*)&lo;
        }
        yh[s] = hh; yl[s] = ll;
    }

    // ---- S-tiles: wave w covers g-tiles w*4 .. w*4+3 ----
    f32x4 acc[4] = {};
    #pragma unroll
    for (int j = 0; j < 4; ++j) {
        const int gt = w * 4 + j;
        const size_t qb = (((size_t)b * 32 + gt) << 11) + (size_t)lane * 8;
        #pragma unroll
        for (int s = 0; s < 4; ++s) {
            short8 qh = *(const short8*)(Phi + qb + s * 512);
            short8 ql = *(const short8*)(Plo + qb + s * 512);
            acc[j] = __builtin_amdgcn_mfma_f32_16x16x32_bf16(yh[s], qh, acc[j], 0, 0, 0);
            acc[j] = __builtin_amdgcn_mfma_f32_16x16x32_bf16(yh[s], ql, acc[j], 0, 0, 0);
            acc[j] = __builtin_amdgcn_mfma_f32_16x16x32_bf16(yl[s], qh, acc[j], 0, 0, 0);
        }
    }

    // ---- streaming softmax partials over this wave's 64 g-cols ----
    #pragma unroll
    for (int r = 0; r < 4; ++r) {
        float vv[4];
        #pragma unroll
        for (int j = 0; j < 4; ++j) vv[j] = acc[j][r] * (1.0f / 16.0f);  // /SCALE
        float mx = fmaxf(fmaxf(vv[0], vv[1]), fmaxf(vv[2], vv[3]));
        #pragma unroll
        for (int off = 8; off; off >>= 1) mx = fmaxf(mx, __shfl_xor(mx, off));
        float se = 0.f, de = 0.f;
        #pragma unroll
        for (int j = 0; j < 4; ++j) {
            float p = expf(vv[j] - mx);
            se += p;
            de += p * xm[(w * 4 + j) * 16 + col];
        }
        #pragma unroll
        for (int off = 8; off; off >>= 1) {
            se += __shfl_xor(se, off);
            de += __shfl_xor(de, off);
        }
        if (col == 0) {
            cm[w][quad * 4 + r] = mx;
            cs[w][quad * 4 + r] = se;
            cd[w][quad * 4 + r] = de;
        }
    }
    __syncthreads();
    if (tid < 16) {
        float Mx = cm[0][tid];
        #pragma unroll
        for (int ww = 1; ww < 8; ++ww) Mx = fmaxf(Mx, cm[ww][tid]);
        float Sx = 0.f, Dx = 0.f;
        #pragma unroll
        for (int ww = 0; ww < 8; ++ww) {
            float e = expf(cm[ww][tid] - Mx);
            Sx += cs[ww][tid] * e;
            Dx += cd[ww][tid] * e;
        }
        fw[((size_t)b << 9) + ft * 16 + tid] = Dx / Sx;
    }
}

// ---------------- K3: per-batch min/max normalize + out = x * fw_n ----------
// out is write-once streaming data: non-temporal stores keep the 131 MB
// output stream from evicting x in L3 (x was pulled in by k_pool and is
// re-read here; keeping it L3-resident saves ~half the x re-fetch from HBM).
// NOTE: __builtin_nontemporal_store requires a clang vector type (f32x4),
// not HIP_vector_type float4.
__global__ __launch_bounds__(256) void k_scale(const float* __restrict__ x,
                                               const float* __restrict__ fw,
                                               float* __restrict__ out) {
    const int row = blockIdx.x;
    const int b   = row >> 9;
    const int tid = threadIdx.x;
    const float* fb = fw + ((size_t)b << 9);
    float v0 = fb[tid], v1 = fb[tid + 256];
    float mi = fminf(v0, v1), ma = fmaxf(v0, v1);
    #pragma unroll
    for (int off = 32; off; off >>= 1) {
        mi = fminf(mi, __shfl_xor(mi, off));
        ma = fmaxf(ma, __shfl_xor(ma, off));
    }
    __shared__ float smi[4], sma[4];
    if ((tid & 63) == 0) { smi[tid >> 6] = mi; sma[tid >> 6] = ma; }
    __syncthreads();
    mi = fminf(fminf(smi[0], smi[1]), fminf(smi[2], smi[3]));
    ma = fmaxf(fmaxf(sma[0], sma[1]), fmaxf(sma[2], sma[3]));
    const float s = (fw[row] - mi) / (ma - mi) + 1e-6f;

    const f32x4* xr = (const f32x4*)(x + (size_t)row * T_);
    f32x4* orow = (f32x4*)(out + (size_t)row * T_);
    for (int i = tid; i < T_/4; i += 256) {
        f32x4 vv = xr[i];
        vv *= s;
        __builtin_nontemporal_store(vv, &orow[i]);
    }
}

extern "C" void kernel_launch(void* const* d_in, const int* in_sizes, int n_in,
                              void* d_out, int out_size, void* d_ws, size_t ws_size,
                              hipStream_t stream) {
    const float* x  = (const float*)d_in[0];
    const float* Wk = (const float*)d_in[1];
    const float* bk = (const float*)d_in[2];
    const float* Wq = (const float*)d_in[3];
    const float* bq = (const float*)d_in[4];
    (void)bq;  // cancels in softmax (row-constant); not needed
    float* out = (float*)d_out;

    float* ws    = (float*)d_ws;
    float* xmean = ws;                                   // 8192 f32
    float* fw    = xmean + ROWS;                         // 8192 f32
    float* v     = fw + ROWS;                            // 128 f32
    short* Mhi   = (short*)(v + E2);                     // 128*128 bf16 bits
    short* Mlo   = Mhi + (size_t)E2 * E2;
    short* Phi   = Mlo + (size_t)E2 * E2;                // 8192*128 bf16 bits
    short* Plo   = Phi + (size_t)ROWS * E2;

    k_pool<<<ROWS + PREP_BLOCKS, 256, 0, stream>>>(x, Wk, Wq, bk,
                                                   Phi, Plo, Mhi, Mlo, v, xmean);
    k_att<<<dim3(F_/16, B_), 512, 0, stream>>>(Phi, Plo, Mhi, Mlo, v, xmean, fw);
    k_scale<<<ROWS, 256, 0, stream>>>(x, fw, out);
}